// Round 15
// baseline (153.244 us; speedup 1.0000x reference)
//
#include <hip/hip_runtime.h>

typedef unsigned short u16;
typedef __attribute__((ext_vector_type(8))) short bf16x8;
typedef __attribute__((ext_vector_type(4))) float f32x4;
typedef __attribute__((ext_vector_type(4))) unsigned u32x4;

#define DEVI __device__ __forceinline__

// Problem dims (fixed)
static constexpr int B_ = 4, T1 = 1024, T2 = 2048, F = 1024, H = 16, DK = 64;

typedef __attribute__((address_space(3))) unsigned lds_u32;
typedef __attribute__((address_space(1))) const unsigned gmem_u32;

DEVI u16 f2bf(float f) {                       // RNE
    union { float f; unsigned u; } c; c.f = f;
    unsigned u = c.u + 0x7fffu + ((c.u >> 16) & 1u);
    return (u16)(u >> 16);
}

// ---------------- cast f32 -> bf16 for x and memory in one launch ----------------
__global__ __launch_bounds__(256) void cast2_bf16_k(const float* __restrict__ a, u16* __restrict__ da, int na,
                                                    const float* __restrict__ b, u16* __restrict__ db, int ntot) {
    int i = (blockIdx.x * 256 + threadIdx.x) * 4;
    if (i >= ntot) return;
    const float* s = (i < na) ? a : b;
    u16* d = (i < na) ? da : db;
    int off = (i < na) ? i : i - na;
    float4 v = *(const float4*)(s + off);
    ushort4 o;
    o.x = f2bf(v.x); o.y = f2bf(v.y); o.z = f2bf(v.z); o.w = f2bf(v.w);
    *(ushort4*)(d + off) = o;
}

// ------------- transpose + cast: W[K,N] f32 -> Wt[N,K] bf16 (z selects src/dst) ----
__global__ __launch_bounds__(256) void transpose_cast_k(const float* __restrict__ src0,
                                                        u16* __restrict__ dst0,
                                                        const float* __restrict__ src1,
                                                        u16* __restrict__ dst1,
                                                        int K, int N) {
    const float* src = blockIdx.z ? src1 : src0;
    u16* dst = blockIdx.z ? dst1 : dst0;
    __shared__ float tile[64][65];
    int kb = blockIdx.x * 64, nb = blockIdx.y * 64;
    int tx = threadIdx.x & 63, ty = threadIdx.x >> 6;   // 64 x 4
#pragma unroll
    for (int p = 0; p < 16; ++p) {
        int r = p * 4 + ty;
        tile[r][tx] = src[(size_t)(kb + r) * N + nb + tx];
    }
    __syncthreads();
#pragma unroll
    for (int p = 0; p < 16; ++p) {
        int r = p * 4 + ty;                              // n-offset
        dst[(size_t)(nb + r) * K + kb + tx] = f2bf(tile[tx][r]);
    }
}

// ------------- bf16 MFMA GEMM, double-buffered single-barrier (proven r14) -------
template <bool OUT_BF16, int WM, int WN>
__global__ __launch_bounds__(256) void gemm_k(const u16* __restrict__ A,
                                              const u16* __restrict__ Bt,
                                              const float* __restrict__ bias,
                                              float scale,
                                              void* __restrict__ Cout,
                                              int M, int N, int K) {
    constexpr int BM = 2 * WM, BN = 2 * WN;
    __shared__ u16 ldsA[2][BM * 64];
    __shared__ u16 ldsB[2][BN * 64];
    const int t = threadIdx.x;
    const int w = t >> 6, lane = t & 63;
    const int wr = w >> 1, wc = w & 1;
    const int lr = lane & 15, lg = lane >> 4;

    const int r0 = t >> 3;
    const int cl = (t & 7) ^ (r0 & 7);
    const u16* Ag = A + (size_t)(blockIdx.x * BM + r0) * K + cl * 8;
    const u16* Bg = Bt + (size_t)(blockIdx.y * BN + r0) * K + cl * 8;

#define GSTAGE(BUF, KOFF) \
    { \
        _Pragma("unroll") \
        for (int i_ = 0; i_ < BM / 32; ++i_) \
            __builtin_amdgcn_global_load_lds( \
                (gmem_u32*)(Ag + (size_t)i_ * 32 * K + (KOFF)), \
                (lds_u32*)((char*)&ldsA[BUF][0] + i_ * 4096 + w * 1024), 16, 0, 0); \
        _Pragma("unroll") \
        for (int i_ = 0; i_ < BN / 32; ++i_) \
            __builtin_amdgcn_global_load_lds( \
                (gmem_u32*)(Bg + (size_t)i_ * 32 * K + (KOFF)), \
                (lds_u32*)((char*)&ldsB[BUF][0] + i_ * 4096 + w * 1024), 16, 0, 0); \
    }

    f32x4 acc[WM / 16][WN / 16] = {};

    GSTAGE(0, 0);
    __syncthreads();

    int buf = 0;
    for (int k0 = 0; k0 < K; k0 += 64) {
        if (k0 + 64 < K) GSTAGE(buf ^ 1, k0 + 64);

        bf16x8 a[2][WM / 16], b[2][WN / 16];
#pragma unroll
        for (int kk = 0; kk < 2; ++kk) {
#pragma unroll
            for (int m = 0; m < WM / 16; ++m) {
                int ra = wr * WM + m * 16 + lr;
                a[kk][m] = *(const bf16x8*)&ldsA[buf][ra * 64 + (((kk * 4 + lg) ^ (ra & 7)) * 8)];
            }
#pragma unroll
            for (int n = 0; n < WN / 16; ++n) {
                int rb = wc * WN + n * 16 + lr;
                b[kk][n] = *(const bf16x8*)&ldsB[buf][rb * 64 + (((kk * 4 + lg) ^ (rb & 7)) * 8)];
            }
        }
#pragma unroll
        for (int kk = 0; kk < 2; ++kk)
#pragma unroll
            for (int m = 0; m < WM / 16; ++m)
#pragma unroll
                for (int n = 0; n < WN / 16; ++n)
                    acc[m][n] = __builtin_amdgcn_mfma_f32_16x16x32_bf16(a[kk][m], b[kk][n], acc[m][n], 0, 0, 0);
        __syncthreads();   // drains this iter's prefetch; next buf ready
        buf ^= 1;
    }

    const int rbase = blockIdx.x * BM + wr * WM;
    const int cbase = blockIdx.y * BN + wc * WN;
#pragma unroll
    for (int m = 0; m < WM / 16; ++m)
#pragma unroll
        for (int n = 0; n < WN / 16; ++n) {
            int col = cbase + n * 16 + lr;
            float bv = bias ? bias[col] : 0.f;
#pragma unroll
            for (int j = 0; j < 4; ++j) {
                int row = rbase + m * 16 + lg * 4 + j;
                float v = (acc[m][n][j] + bv) * scale;
                if (OUT_BF16)
                    ((u16*)Cout)[(size_t)row * N + col] = f2bf(v);
                else
                    ((float*)Cout)[(size_t)row * N + col] = v;
            }
        }
#undef GSTAGE
}

// ------------- KV projection GEMM with fused V transpose, double-buffered (r14) ----
__global__ __launch_bounds__(256) void gemm_kv_k(const u16* __restrict__ A,   // mb [B*T2, F]
                                                 const u16* __restrict__ Bt,  // Wkvt [2F, F]
                                                 const float* __restrict__ bias,
                                                 u16* __restrict__ Kb,        // [B*T2, F]
                                                 u16* __restrict__ Vt) {      // [B*H*DK, T2]
    constexpr int K = F, N = F;
    __shared__ u16 smem[4][128 * 64];  // 64 KB
    const int t = threadIdx.x;
    const int w = t >> 6, lane = t & 63;
    const int wr = w >> 1, wc = w & 1;
    const int lr = lane & 15, lg = lane >> 4;

    const int r0 = t >> 3;
    const int cl = (t & 7) ^ (r0 & 7);
    const u16* Ag = A + (size_t)(blockIdx.x * 128 + r0) * K + cl * 8;
    const u16* Bg = Bt + (size_t)(blockIdx.y * 128 + r0) * K + cl * 8;

#define KVSTAGE(BUF, KOFF) \
    { \
        _Pragma("unroll") \
        for (int i_ = 0; i_ < 4; ++i_) { \
            __builtin_amdgcn_global_load_lds( \
                (gmem_u32*)(Ag + (size_t)i_ * 32 * K + (KOFF)), \
                (lds_u32*)((char*)&smem[BUF][0] + i_ * 4096 + w * 1024), 16, 0, 0); \
            __builtin_amdgcn_global_load_lds( \
                (gmem_u32*)(Bg + (size_t)i_ * 32 * K + (KOFF)), \
                (lds_u32*)((char*)&smem[2 + (BUF)][0] + i_ * 4096 + w * 1024), 16, 0, 0); \
        } \
    }

    f32x4 acc[4][4] = {};

    KVSTAGE(0, 0);
    __syncthreads();

    int buf = 0;
    for (int k0 = 0; k0 < K; k0 += 64) {
        if (k0 + 64 < K) KVSTAGE(buf ^ 1, k0 + 64);

        bf16x8 a[2][4], b[2][4];
#pragma unroll
        for (int kk = 0; kk < 2; ++kk)
#pragma unroll
            for (int m = 0; m < 4; ++m) {
                int ra = wr * 64 + m * 16 + lr;
                int rb = wc * 64 + m * 16 + lr;
                a[kk][m] = *(const bf16x8*)&smem[buf][ra * 64 + (((kk * 4 + lg) ^ (ra & 7)) * 8)];
                b[kk][m] = *(const bf16x8*)&smem[2 + buf][rb * 64 + (((kk * 4 + lg) ^ (rb & 7)) * 8)];
            }
#pragma unroll
        for (int kk = 0; kk < 2; ++kk)
#pragma unroll
            for (int m = 0; m < 4; ++m)
#pragma unroll
                for (int n = 0; n < 4; ++n)
                    acc[m][n] = __builtin_amdgcn_mfma_f32_16x16x32_bf16(a[kk][m], b[kk][n], acc[m][n], 0, 0, 0);
        __syncthreads();
        buf ^= 1;
    }

    const int rbase = blockIdx.x * 128 + wr * 64;
    if (blockIdx.y < 8) {
        const int cbase = blockIdx.y * 128 + wc * 64;
#pragma unroll
        for (int m = 0; m < 4; ++m)
#pragma unroll
            for (int n = 0; n < 4; ++n) {
                int col = cbase + n * 16 + lr;
                float bv = bias[col];
#pragma unroll
                for (int j = 0; j < 4; ++j) {
                    int row = rbase + m * 16 + lg * 4 + j;
                    Kb[(size_t)row * N + col] = f2bf(acc[m][n][j] + bv);
                }
            }
    } else {
        // V half: bias, bf16, transpose via LDS (flat 64 KB area, stride 136)
        u16* tbuf = &smem[0][0];
        const int cb2 = (blockIdx.y - 8) * 128;
#pragma unroll
        for (int m = 0; m < 4; ++m)
#pragma unroll
            for (int n = 0; n < 4; ++n) {
                int c = wc * 64 + n * 16 + lr;
                float bv = bias[F + cb2 + c];
#pragma unroll
                for (int j = 0; j < 4; ++j) {
                    int r = wr * 64 + m * 16 + lg * 4 + j;
                    int np = ((r >> 2) & 3) * 16 + ((r >> 5) & 1) * 8 + ((r >> 4) & 1) * 4 + (r & 3) + (r & 64);
                    tbuf[c * 136 + np] = f2bf(acc[m][n][j] + bv);
                }
            }
        __syncthreads();
        const int c = t >> 1, half = t & 1;
        const int rb = blockIdx.x * 128;
        const int b = rb >> 11, t2b = rb & 2047;
        const int vcol = cb2 + c;
        const int hh = vcol >> 6, d = vcol & 63;
        u16* dst = Vt + ((size_t)((b * H + hh) * DK + d)) * T2 + t2b + half * 64;
        const u16* srcp = &tbuf[c * 136 + half * 64];
#pragma unroll
        for (int i = 0; i < 8; ++i)
            *(uint4*)(dst + i * 8) = *(const uint4*)(srcp + i * 8);
    }
#undef KVSTAGE
}

// fixed-offset softmax + P pack: P = 2^S via raw v_exp_f32; cvt_pk pack (r13).
#define SOFTMAX_PACK(S, PA0, PA1) \
    { \
        float pv_[4][4]; \
        _Pragma("unroll") \
        for (int ss_ = 0; ss_ < 4; ++ss_) \
            _Pragma("unroll") \
            for (int j_ = 0; j_ < 4; ++j_) \
                pv_[ss_][j_] = __builtin_amdgcn_exp2f(S[ss_][j_]); \
        u32x4 pw0_, pw1_; \
        asm("v_cvt_pk_bf16_f32 %0, %1, %2" : "=v"(pw0_[0]) : "v"(pv_[0][0]), "v"(pv_[0][1])); \
        asm("v_cvt_pk_bf16_f32 %0, %1, %2" : "=v"(pw0_[1]) : "v"(pv_[0][2]), "v"(pv_[0][3])); \
        asm("v_cvt_pk_bf16_f32 %0, %1, %2" : "=v"(pw0_[2]) : "v"(pv_[1][0]), "v"(pv_[1][1])); \
        asm("v_cvt_pk_bf16_f32 %0, %1, %2" : "=v"(pw0_[3]) : "v"(pv_[1][2]), "v"(pv_[1][3])); \
        asm("v_cvt_pk_bf16_f32 %0, %1, %2" : "=v"(pw1_[0]) : "v"(pv_[2][0]), "v"(pv_[2][1])); \
        asm("v_cvt_pk_bf16_f32 %0, %1, %2" : "=v"(pw1_[1]) : "v"(pv_[2][2]), "v"(pv_[2][3])); \
        asm("v_cvt_pk_bf16_f32 %0, %1, %2" : "=v"(pw1_[2]) : "v"(pv_[3][0]), "v"(pv_[3][1])); \
        asm("v_cvt_pk_bf16_f32 %0, %1, %2" : "=v"(pw1_[3]) : "v"(pv_[3][2]), "v"(pv_[3][3])); \
        PA0 = __builtin_bit_cast(bf16x8, pw0_); \
        PA1 = __builtin_bit_cast(bf16x8, pw1_); \
    }

// ------------- fused flash-style cross attention v8: in-block k-split -------------
// 512 threads / 8 waves; group g = w>>2 handles k-tiles kt = 2i+g. Each group has
// its own double-buffered K/V LDS pair -> per-CU staging totals unchanged vs r13,
// but 16 waves/CU (2x occupancy). Fixed-offset softmax makes the cross-group
// combine exact: partial unnormalized O + lsum added in LDS (XOR-swizzled f32x4
// layout, conflict-free), then one normalize+store by group 0.
__global__ __launch_bounds__(512) void attn_k(const u16* __restrict__ Qb,   // [B*T1, F] (pre-scaled)
                                              const u16* __restrict__ Kb,   // [B*T2, F]
                                              const u16* __restrict__ Vt,   // [B*H*DK, T2] (col-permuted)
                                              const int* __restrict__ mask, // [B, T2]
                                              u16* __restrict__ attO) {     // [B*T1, F]
    __shared__ u16 ldsK[2][2][64 * 64];   // [group][parity] 32 KB
    __shared__ u16 ldsV[2][2][64 * 64];   // 32 KB
    __shared__ float smaskf[T2];          // 8 KB: -16 or -1e30

    const int h = blockIdx.x, q0 = blockIdx.y * 128, b = blockIdx.z;
    const int w = threadIdx.x >> 6, lane = threadIdx.x & 63;
    const int g = w >> 2, wg = w & 3;
    const int lr = lane & 15, lg = lane >> 4;

    for (int i = threadIdx.x; i < T2; i += 512)
        smaskf[i] = mask[b * T2 + i] ? -16.f : -1e30f;

    // Q fragments (B-operand: lane holds q-row base+lr, d = 8*lg+j); both groups
    // load the same rows (wg-indexed) -- duplicated, trivial.
    const u16* qptrA = Qb + (size_t)(b * T1 + q0 + wg * 32 + lr) * F + h * DK + lg * 8;
    const bf16x8 qA0 = *(const bf16x8*)(qptrA);
    const bf16x8 qA1 = *(const bf16x8*)(qptrA + 32);
    const bf16x8 qB0 = *(const bf16x8*)(qptrA + 16 * F);
    const bf16x8 qB1 = *(const bf16x8*)(qptrA + 16 * F + 32);

    // all-ones bf16 A-fragment for the lsum MFMA
    u32x4 ow; ow[0] = ow[1] = ow[2] = ow[3] = 0x3F803F80u;
    const bf16x8 onesf = __builtin_bit_cast(bf16x8, ow);

    // staging: within a group, waves wg 0,1 stage K; wg 2,3 stage V. 4 instrs each.
    const u16* Kg_ = Kb + (size_t)b * T2 * F + h * DK;
    const u16* Vg_ = Vt + (size_t)(b * H + h) * DK * T2;
    const int sr = (lane >> 3);          // row-in-instr
    const int scd = lane & 7;            // dest chunk

#define STAGE(PB, KT) \
    { \
        if (wg < 2) { \
            _Pragma("unroll") \
            for (int i_ = 0; i_ < 4; ++i_) { \
                int ii_ = (wg & 1) * 4 + i_; \
                int r0_ = ii_ * 8 + sr; \
                int cl_ = scd ^ (r0_ & 7); \
                __builtin_amdgcn_global_load_lds( \
                    (gmem_u32*)(Kg_ + (size_t)((KT) * 64 + r0_) * F + cl_ * 8), \
                    (lds_u32*)((char*)&ldsK[g][PB][0] + ii_ * 1024), 16, 0, 0); \
            } \
        } else { \
            _Pragma("unroll") \
            for (int i_ = 0; i_ < 4; ++i_) { \
                int ii_ = (wg & 1) * 4 + i_; \
                int r0_ = ii_ * 8 + sr; \
                int cl_ = scd ^ (r0_ & 7); \
                __builtin_amdgcn_global_load_lds( \
                    (gmem_u32*)(Vg_ + (size_t)r0_ * T2 + (KT) * 64 + cl_ * 8), \
                    (lds_u32*)((char*)&ldsV[g][PB][0] + ii_ * 1024), 16, 0, 0); \
            } \
        } \
    }

    f32x4 oA[4] = {}, oB[4] = {};
    f32x4 lsA4 = {}, lsB4 = {};

    STAGE(0, g);
    __syncthreads();

    int buf = 0;
    for (int i = 0; i < 16; ++i) {
        const int kt = 2 * i + g;
        if (i < 15) STAGE(buf ^ 1, kt + 2);

        // ---- fragment reads from LDS (swizzled) ----
        bf16x8 kf[4][2], vf[2][4];
#pragma unroll
        for (int ss = 0; ss < 4; ++ss) {
            int row = ss * 16 + lr;
            kf[ss][0] = *(const bf16x8*)&ldsK[g][buf][row * 64 + ((lg ^ (row & 7)) * 8)];
            kf[ss][1] = *(const bf16x8*)&ldsK[g][buf][row * 64 + (((4 + lg) ^ (row & 7)) * 8)];
        }
#pragma unroll
        for (int m = 0; m < 2; ++m)
#pragma unroll
            for (int d = 0; d < 4; ++d) {
                int row = d * 16 + lr;
                vf[m][d] = *(const bf16x8*)&ldsV[g][buf][row * 64 + (((lg * 2 + m) ^ (row & 7)) * 8)];
            }

        // ---- S^T = K Q^T + C(mask - 16), both q-fragments ----
        f32x4 sA[4], sB[4];
#pragma unroll
        for (int ss = 0; ss < 4; ++ss) {
            f32x4 c = *(const f32x4*)&smaskf[kt * 64 + ss * 16 + lg * 4];
            sA[ss] = c; sB[ss] = c;
        }
        __builtin_amdgcn_s_setprio(1);
#pragma unroll
        for (int ss = 0; ss < 4; ++ss) {
            sA[ss] = __builtin_amdgcn_mfma_f32_16x16x32_bf16(kf[ss][0], qA0, sA[ss], 0, 0, 0);
            sB[ss] = __builtin_amdgcn_mfma_f32_16x16x32_bf16(kf[ss][0], qB0, sB[ss], 0, 0, 0);
            sA[ss] = __builtin_amdgcn_mfma_f32_16x16x32_bf16(kf[ss][1], qA1, sA[ss], 0, 0, 0);
            sB[ss] = __builtin_amdgcn_mfma_f32_16x16x32_bf16(kf[ss][1], qB1, sB[ss], 0, 0, 0);
        }
        __builtin_amdgcn_s_setprio(0);

        // ---- P = 2^S, pack (raw v_exp_f32 + cvt_pk) ----
        bf16x8 paA0, paA1, paB0, paB1;
        SOFTMAX_PACK(sA, paA0, paA1);
        SOFTMAX_PACK(sB, paB0, paB1);

        // ---- O^T += V^T P^T ; lsum += 1^T P^T (ones-MFMA) ----
        __builtin_amdgcn_s_setprio(1);
#pragma unroll
        for (int d = 0; d < 4; ++d) {
            oA[d] = __builtin_amdgcn_mfma_f32_16x16x32_bf16(vf[0][d], paA0, oA[d], 0, 0, 0);
            oB[d] = __builtin_amdgcn_mfma_f32_16x16x32_bf16(vf[0][d], paB0, oB[d], 0, 0, 0);
        }
        lsA4 = __builtin_amdgcn_mfma_f32_16x16x32_bf16(onesf, paA0, lsA4, 0, 0, 0);
        lsB4 = __builtin_amdgcn_mfma_f32_16x16x32_bf16(onesf, paB0, lsB4, 0, 0, 0);
#pragma unroll
        for (int d = 0; d < 4; ++d) {
            oA[d] = __builtin_amdgcn_mfma_f32_16x16x32_bf16(vf[1][d], paA1, oA[d], 0, 0, 0);
            oB[d] = __builtin_amdgcn_mfma_f32_16x16x32_bf16(vf[1][d], paB1, oB[d], 0, 0, 0);
        }
        lsA4 = __builtin_amdgcn_mfma_f32_16x16x32_bf16(onesf, paA1, lsA4, 0, 0, 0);
        lsB4 = __builtin_amdgcn_mfma_f32_16x16x32_bf16(onesf, paB1, lsB4, 0, 0, 0);
        __builtin_amdgcn_s_setprio(0);

        __syncthreads();   // all waves done with their buf; next bufs staged
        buf ^= 1;
    }

    // ---- cross-group combine via LDS (reuse ldsK/ldsV; loop's final barrier done) --
    // Layout: 32 floats per (wg,lane); chunk c (f32x4) at idx (c*4) ^ ((lane&7)<<2)
    // -> bijective within the 32-float run, banks spread across all 32.
    float* cO = (float*)&ldsK[0][0][0];   // 32 KB
    float* cL = (float*)&ldsV[0][0][0];   // 2 KB
    const int cb = (wg * 64 + lane) * 32;
    const int sw = (lane & 7) << 2;
    if (g == 1) {
#pragma unroll
        for (int c = 0; c < 4; ++c)
            *(f32x4*)&cO[cb + ((c * 4) ^ sw)] = oA[c];
#pragma unroll
        for (int c = 0; c < 4; ++c)
            *(f32x4*)&cO[cb + (((c + 4) * 4) ^ sw)] = oB[c];
        cL[(wg * 64 + lane) * 2] = lsA4[0];
        cL[(wg * 64 + lane) * 2 + 1] = lsB4[0];
    }
    __syncthreads();
    if (g == 0) {
#pragma unroll
        for (int c = 0; c < 4; ++c)
            oA[c] += *(const f32x4*)&cO[cb + ((c * 4) ^ sw)];
#pragma unroll
        for (int c = 0; c < 4; ++c)
            oB[c] += *(const f32x4*)&cO[cb + (((c + 4) * 4) ^ sw)];
        float lA = lsA4[0] + cL[(wg * 64 + lane) * 2];
        float lB = lsB4[0] + cL[(wg * 64 + lane) * 2 + 1];
        float invA = lA > 0.f ? 1.f / lA : 1.f;
        float invB = lB > 0.f ? 1.f / lB : 1.f;
        const size_t obase = (size_t)(b * T1 + q0 + wg * 32 + lr) * F + h * DK;
#pragma unroll
        for (int d = 0; d < 4; ++d) {
            ushort4 oa, ob;
            oa.x = f2bf(oA[d][0] * invA); oa.y = f2bf(oA[d][1] * invA);
            oa.z = f2bf(oA[d][2] * invA); oa.w = f2bf(oA[d][3] * invA);
            ob.x = f2bf(oB[d][0] * invB); ob.y = f2bf(oB[d][1] * invB);
            ob.z = f2bf(oB[d][2] * invB); ob.w = f2bf(oB[d][3] * invB);
            *(ushort4*)&attO[obase + d * 16 + lg * 4] = oa;
            *(ushort4*)&attO[obase + 16 * F + d * 16 + lg * 4] = ob;
        }
    }
}

extern "C" void kernel_launch(void* const* d_in, const int* in_sizes, int n_in,
                              void* d_out, int out_size, void* d_ws, size_t ws_size,
                              hipStream_t stream) {
    const float* x      = (const float*)d_in[0];
    const float* memory = (const float*)d_in[1];
    const int*   mmask  = (const int*)d_in[2];
    const float* Wq     = (const float*)d_in[3];
    const float* bq     = (const float*)d_in[4];
    const float* Wkv    = (const float*)d_in[5];
    const float* bkv    = (const float*)d_in[6];
    const float* Wo     = (const float*)d_in[7];
    const float* bo     = (const float*)d_in[8];
    float* out = (float*)d_out;
    char* ws = (char*)d_ws;

    // workspace layout (72 MB total)
    u16* xb   = (u16*)(ws);                  // [4096,1024]  8 MB   (reused as attO)
    u16* mb   = (u16*)(ws + (8u  << 20));    // [8192,1024] 16 MB
    u16* Wqt  = (u16*)(ws + (24u << 20));    // [1024,1024]  2 MB
    u16* Wkvt = (u16*)(ws + (26u << 20));    // [2048,1024]  4 MB
    u16* Wot  = (u16*)(ws + (30u << 20));    // [1024,1024]  2 MB
    u16* Qb   = (u16*)(ws + (32u << 20));    // [4096,1024]  8 MB
    u16* Kb   = (u16*)(ws + (40u << 20));    // [8192,1024] 16 MB
    u16* Vt   = (u16*)(ws + (56u << 20));    // [1024,2048] 16 MB
    u16* attO = xb;

    // 1. casts (x + memory, one launch)
    cast2_bf16_k<<<(B_ * T1 * F + B_ * T2 * F) / 1024, 256, 0, stream>>>(
        x, xb, B_ * T1 * F, memory, mb, B_ * T1 * F + B_ * T2 * F);

    // 2. weight transposes (Wq+Wo fused via z; Wkv separate)
    transpose_cast_k<<<dim3(F / 64, F / 64, 2), 256, 0, stream>>>(Wq, Wqt, Wo, Wot, F, F);
    transpose_cast_k<<<dim3(F / 64, 2 * F / 64, 1), 256, 0, stream>>>(Wkv, Wkvt, Wkv, Wkvt, F, 2 * F);

    // 3. projections (Q pre-scaled by 1/sqrt(dk) * log2(e) for exp2-domain softmax)
    gemm_k<true, 32, 64><<<dim3(B_ * T1 / 64, F / 128), 256, 0, stream>>>(xb, Wqt, bq, 0.125f * 1.44269504f, Qb, B_ * T1, F, F);
    // KV projection with fused V transpose (writes Kb + Vt)
    gemm_kv_k<<<dim3(B_ * T2 / 128, 2 * F / 128), 256, 0, stream>>>(mb, Wkvt, bkv, Kb, Vt);

    // 4. attention (512 threads, in-block k-split, 16 waves/CU)
    attn_k<<<dim3(H, T1 / 128, B_), 512, 0, stream>>>(Qb, Kb, Vt, mmask, attO);

    // 5. output projection (f32 out)
    gemm_k<false, 32, 64><<<dim3(B_ * T1 / 64, F / 128), 256, 0, stream>>>(attO, Wot, bo, 1.f, out, B_ * T1, F, F);
}

// Round 16
// 128.341 us; speedup vs baseline: 1.1940x; 1.1940x over previous
//
#include <hip/hip_runtime.h>

typedef unsigned short u16;
typedef __attribute__((ext_vector_type(8))) short bf16x8;
typedef __attribute__((ext_vector_type(4))) float f32x4;
typedef __attribute__((ext_vector_type(4))) unsigned u32x4;

#define DEVI __device__ __forceinline__

// Problem dims (fixed)
static constexpr int B_ = 4, T1 = 1024, T2 = 2048, F = 1024, H = 16, DK = 64;

typedef __attribute__((address_space(3))) unsigned lds_u32;
typedef __attribute__((address_space(1))) const unsigned gmem_u32;

DEVI u16 f2bf(float f) {                       // RNE
    union { float f; unsigned u; } c; c.f = f;
    unsigned u = c.u + 0x7fffu + ((c.u >> 16) & 1u);
    return (u16)(u >> 16);
}

// ---------------- cast f32 -> bf16 for x and memory in one launch ----------------
__global__ __launch_bounds__(256) void cast2_bf16_k(const float* __restrict__ a, u16* __restrict__ da, int na,
                                                    const float* __restrict__ b, u16* __restrict__ db, int ntot) {
    int i = (blockIdx.x * 256 + threadIdx.x) * 4;
    if (i >= ntot) return;
    const float* s = (i < na) ? a : b;
    u16* d = (i < na) ? da : db;
    int off = (i < na) ? i : i - na;
    float4 v = *(const float4*)(s + off);
    ushort4 o;
    o.x = f2bf(v.x); o.y = f2bf(v.y); o.z = f2bf(v.z); o.w = f2bf(v.w);
    *(ushort4*)(d + off) = o;
}

// ------------- all weight transposes in ONE launch (z: 0=Wq, 1=Wo, 2,3=Wkv halves) --
__global__ __launch_bounds__(256) void transpose_cast4_k(const float* __restrict__ Wq, u16* __restrict__ Wqt,
                                                         const float* __restrict__ Wo, u16* __restrict__ Wot,
                                                         const float* __restrict__ Wkv, u16* __restrict__ Wkvt) {
    const int z = blockIdx.z;
    const float* src; u16* dst; int N, colOff, rowOff;
    if (z == 0)      { src = Wq;  dst = Wqt;  N = F;     colOff = 0; rowOff = 0; }
    else if (z == 1) { src = Wo;  dst = Wot;  N = F;     colOff = 0; rowOff = 0; }
    else             { src = Wkv; dst = Wkvt; N = 2 * F; colOff = (z - 2) * F; rowOff = (z - 2) * F; }
    __shared__ float tile[64][65];
    int kb = blockIdx.x * 64, nb = blockIdx.y * 64;
    int tx = threadIdx.x & 63, ty = threadIdx.x >> 6;   // 64 x 4
#pragma unroll
    for (int p = 0; p < 16; ++p) {
        int r = p * 4 + ty;
        tile[r][tx] = src[(size_t)(kb + r) * N + colOff + nb + tx];
    }
    __syncthreads();
#pragma unroll
    for (int p = 0; p < 16; ++p) {
        int r = p * 4 + ty;                              // n-offset
        dst[(size_t)(rowOff + nb + r) * F + kb + tx] = f2bf(tile[tx][r]);
    }
}

// ------------- bf16 MFMA GEMM, double-buffered single-barrier (proven r14) -------
// Used for O-proj only now.
template <bool OUT_BF16, int WM, int WN>
__global__ __launch_bounds__(256) void gemm_k(const u16* __restrict__ A,
                                              const u16* __restrict__ Bt,
                                              const float* __restrict__ bias,
                                              float scale,
                                              void* __restrict__ Cout,
                                              int M, int N, int K) {
    constexpr int BM = 2 * WM, BN = 2 * WN;
    __shared__ u16 ldsA[2][BM * 64];
    __shared__ u16 ldsB[2][BN * 64];
    const int t = threadIdx.x;
    const int w = t >> 6, lane = t & 63;
    const int wr = w >> 1, wc = w & 1;
    const int lr = lane & 15, lg = lane >> 4;

    const int r0 = t >> 3;
    const int cl = (t & 7) ^ (r0 & 7);
    const u16* Ag = A + (size_t)(blockIdx.x * BM + r0) * K + cl * 8;
    const u16* Bg = Bt + (size_t)(blockIdx.y * BN + r0) * K + cl * 8;

#define GSTAGE(BUF, KOFF) \
    { \
        _Pragma("unroll") \
        for (int i_ = 0; i_ < BM / 32; ++i_) \
            __builtin_amdgcn_global_load_lds( \
                (gmem_u32*)(Ag + (size_t)i_ * 32 * K + (KOFF)), \
                (lds_u32*)((char*)&ldsA[BUF][0] + i_ * 4096 + w * 1024), 16, 0, 0); \
        _Pragma("unroll") \
        for (int i_ = 0; i_ < BN / 32; ++i_) \
            __builtin_amdgcn_global_load_lds( \
                (gmem_u32*)(Bg + (size_t)i_ * 32 * K + (KOFF)), \
                (lds_u32*)((char*)&ldsB[BUF][0] + i_ * 4096 + w * 1024), 16, 0, 0); \
    }

    f32x4 acc[WM / 16][WN / 16] = {};

    GSTAGE(0, 0);
    __syncthreads();

    int buf = 0;
    for (int k0 = 0; k0 < K; k0 += 64) {
        if (k0 + 64 < K) GSTAGE(buf ^ 1, k0 + 64);

        bf16x8 a[2][WM / 16], b[2][WN / 16];
#pragma unroll
        for (int kk = 0; kk < 2; ++kk) {
#pragma unroll
            for (int m = 0; m < WM / 16; ++m) {
                int ra = wr * WM + m * 16 + lr;
                a[kk][m] = *(const bf16x8*)&ldsA[buf][ra * 64 + (((kk * 4 + lg) ^ (ra & 7)) * 8)];
            }
#pragma unroll
            for (int n = 0; n < WN / 16; ++n) {
                int rb = wc * WN + n * 16 + lr;
                b[kk][n] = *(const bf16x8*)&ldsB[buf][rb * 64 + (((kk * 4 + lg) ^ (rb & 7)) * 8)];
            }
        }
#pragma unroll
        for (int kk = 0; kk < 2; ++kk)
#pragma unroll
            for (int m = 0; m < WM / 16; ++m)
#pragma unroll
                for (int n = 0; n < WN / 16; ++n)
                    acc[m][n] = __builtin_amdgcn_mfma_f32_16x16x32_bf16(a[kk][m], b[kk][n], acc[m][n], 0, 0, 0);
        __syncthreads();   // drains this iter's prefetch; next buf ready
        buf ^= 1;
    }

    const int rbase = blockIdx.x * BM + wr * WM;
    const int cbase = blockIdx.y * BN + wc * WN;
#pragma unroll
    for (int m = 0; m < WM / 16; ++m)
#pragma unroll
        for (int n = 0; n < WN / 16; ++n) {
            int col = cbase + n * 16 + lr;
            float bv = bias ? bias[col] : 0.f;
#pragma unroll
            for (int j = 0; j < 4; ++j) {
                int row = rbase + m * 16 + lg * 4 + j;
                float v = (acc[m][n][j] + bv) * scale;
                if (OUT_BF16)
                    ((u16*)Cout)[(size_t)row * N + col] = f2bf(v);
                else
                    ((float*)Cout)[(size_t)row * N + col] = v;
            }
        }
#undef GSTAGE
}

// ------------- fused KV+Q projection GEMM (dbuf, r14 structure) -------------
// grid (64, 20): y<8 -> K half (write Kb, stride F); 8<=y<16 -> V half (fused
// transpose to Vt with NP perm); y>=16 -> Q-proj 128^2 tiles:
// qx = x>>1 in [0,32), qn = (y-16)*2 + (x&1) in [0,8); writes Qb (pre-scaled).
__global__ __launch_bounds__(256) void gemm_kvq_k(const u16* __restrict__ Am,   // mb [B*T2, F]
                                                  const u16* __restrict__ Wkvt, // [2F, F]
                                                  const float* __restrict__ bkv,
                                                  u16* __restrict__ Kb,         // [B*T2, F]
                                                  u16* __restrict__ Vt,         // [B*H*DK, T2]
                                                  const u16* __restrict__ Ax,   // xb [B*T1, F]
                                                  const u16* __restrict__ Wqt,  // [F, F]
                                                  const float* __restrict__ bq,
                                                  u16* __restrict__ Qb,         // [B*T1, F]
                                                  float qscale) {
    constexpr int K = F;
    __shared__ u16 smem[4][128 * 64];  // 64 KB
    const int t = threadIdx.x;
    const int w = t >> 6, lane = t & 63;
    const int wr = w >> 1, wc = w & 1;
    const int lr = lane & 15, lg = lane >> 4;

    const int yy = blockIdx.y;
    const bool isQ = (yy >= 16);
    const int bx = isQ ? (blockIdx.x >> 1) : blockIdx.x;
    const int by = isQ ? ((yy - 16) * 2 + (blockIdx.x & 1)) : yy;
    const u16* Abase = isQ ? Ax : Am;
    const u16* Btbase = isQ ? Wqt : Wkvt;

    const int r0 = t >> 3;
    const int cl = (t & 7) ^ (r0 & 7);
    const u16* Ag = Abase + (size_t)(bx * 128 + r0) * K + cl * 8;
    const u16* Bg = Btbase + (size_t)(by * 128 + r0) * K + cl * 8;

#define KVSTAGE(BUF, KOFF) \
    { \
        _Pragma("unroll") \
        for (int i_ = 0; i_ < 4; ++i_) { \
            __builtin_amdgcn_global_load_lds( \
                (gmem_u32*)(Ag + (size_t)i_ * 32 * K + (KOFF)), \
                (lds_u32*)((char*)&smem[BUF][0] + i_ * 4096 + w * 1024), 16, 0, 0); \
            __builtin_amdgcn_global_load_lds( \
                (gmem_u32*)(Bg + (size_t)i_ * 32 * K + (KOFF)), \
                (lds_u32*)((char*)&smem[2 + (BUF)][0] + i_ * 4096 + w * 1024), 16, 0, 0); \
        } \
    }

    f32x4 acc[4][4] = {};

    KVSTAGE(0, 0);
    __syncthreads();

    int buf = 0;
    for (int k0 = 0; k0 < K; k0 += 64) {
        if (k0 + 64 < K) KVSTAGE(buf ^ 1, k0 + 64);

        bf16x8 a[2][4], b[2][4];
#pragma unroll
        for (int kk = 0; kk < 2; ++kk)
#pragma unroll
            for (int m = 0; m < 4; ++m) {
                int ra = wr * 64 + m * 16 + lr;
                int rb = wc * 64 + m * 16 + lr;
                a[kk][m] = *(const bf16x8*)&smem[buf][ra * 64 + (((kk * 4 + lg) ^ (ra & 7)) * 8)];
                b[kk][m] = *(const bf16x8*)&smem[2 + buf][rb * 64 + (((kk * 4 + lg) ^ (rb & 7)) * 8)];
            }
#pragma unroll
        for (int kk = 0; kk < 2; ++kk)
#pragma unroll
            for (int m = 0; m < 4; ++m)
#pragma unroll
                for (int n = 0; n < 4; ++n)
                    acc[m][n] = __builtin_amdgcn_mfma_f32_16x16x32_bf16(a[kk][m], b[kk][n], acc[m][n], 0, 0, 0);
        __syncthreads();
        buf ^= 1;
    }

    const int rbase = bx * 128 + wr * 64;
    if (isQ) {
        // Q-proj: write Qb [B*T1, F], bias bq, scale qscale, bf16
        const int cbase = by * 128 + wc * 64;
#pragma unroll
        for (int m = 0; m < 4; ++m)
#pragma unroll
            for (int n = 0; n < 4; ++n) {
                int col = cbase + n * 16 + lr;
                float bv = bq[col];
#pragma unroll
                for (int j = 0; j < 4; ++j) {
                    int row = rbase + m * 16 + lg * 4 + j;
                    Qb[(size_t)row * F + col] = f2bf((acc[m][n][j] + bv) * qscale);
                }
            }
    } else if (yy < 8) {
        // K half: normal coalesced write, output stride F
        const int cbase = yy * 128 + wc * 64;
#pragma unroll
        for (int m = 0; m < 4; ++m)
#pragma unroll
            for (int n = 0; n < 4; ++n) {
                int col = cbase + n * 16 + lr;
                float bv = bkv[col];
#pragma unroll
                for (int j = 0; j < 4; ++j) {
                    int row = rbase + m * 16 + lg * 4 + j;
                    Kb[(size_t)row * F + col] = f2bf(acc[m][n][j] + bv);
                }
            }
    } else {
        // V half: bias, bf16, transpose via LDS (flat 64 KB area, stride 136)
        u16* tbuf = &smem[0][0];
        const int cb2 = (yy - 8) * 128;
#pragma unroll
        for (int m = 0; m < 4; ++m)
#pragma unroll
            for (int n = 0; n < 4; ++n) {
                int c = wc * 64 + n * 16 + lr;
                float bv = bkv[F + cb2 + c];
#pragma unroll
                for (int j = 0; j < 4; ++j) {
                    int r = wr * 64 + m * 16 + lg * 4 + j;
                    int np = ((r >> 2) & 3) * 16 + ((r >> 5) & 1) * 8 + ((r >> 4) & 1) * 4 + (r & 3) + (r & 64);
                    tbuf[c * 136 + np] = f2bf(acc[m][n][j] + bv);
                }
            }
        __syncthreads();
        const int c = t >> 1, half = t & 1;
        const int rb = bx * 128;
        const int b = rb >> 11, t2b = rb & 2047;
        const int vcol = cb2 + c;
        const int hh = vcol >> 6, d = vcol & 63;
        u16* dst = Vt + ((size_t)((b * H + hh) * DK + d)) * T2 + t2b + half * 64;
        const u16* srcp = &tbuf[c * 136 + half * 64];
#pragma unroll
        for (int i = 0; i < 8; ++i)
            *(uint4*)(dst + i * 8) = *(const uint4*)(srcp + i * 8);
    }
#undef KVSTAGE
}

// fixed-offset softmax + P pack: P = 2^S via raw v_exp_f32; cvt_pk pack (r13).
#define SOFTMAX_PACK(S, PA0, PA1) \
    { \
        float pv_[4][4]; \
        _Pragma("unroll") \
        for (int ss_ = 0; ss_ < 4; ++ss_) \
            _Pragma("unroll") \
            for (int j_ = 0; j_ < 4; ++j_) \
                pv_[ss_][j_] = __builtin_amdgcn_exp2f(S[ss_][j_]); \
        u32x4 pw0_, pw1_; \
        asm("v_cvt_pk_bf16_f32 %0, %1, %2" : "=v"(pw0_[0]) : "v"(pv_[0][0]), "v"(pv_[0][1])); \
        asm("v_cvt_pk_bf16_f32 %0, %1, %2" : "=v"(pw0_[1]) : "v"(pv_[0][2]), "v"(pv_[0][3])); \
        asm("v_cvt_pk_bf16_f32 %0, %1, %2" : "=v"(pw0_[2]) : "v"(pv_[1][0]), "v"(pv_[1][1])); \
        asm("v_cvt_pk_bf16_f32 %0, %1, %2" : "=v"(pw0_[3]) : "v"(pv_[1][2]), "v"(pv_[1][3])); \
        asm("v_cvt_pk_bf16_f32 %0, %1, %2" : "=v"(pw1_[0]) : "v"(pv_[2][0]), "v"(pv_[2][1])); \
        asm("v_cvt_pk_bf16_f32 %0, %1, %2" : "=v"(pw1_[1]) : "v"(pv_[2][2]), "v"(pv_[2][3])); \
        asm("v_cvt_pk_bf16_f32 %0, %1, %2" : "=v"(pw1_[2]) : "v"(pv_[3][0]), "v"(pv_[3][1])); \
        asm("v_cvt_pk_bf16_f32 %0, %1, %2" : "=v"(pw1_[3]) : "v"(pv_[3][2]), "v"(pv_[3][3])); \
        PA0 = __builtin_bit_cast(bf16x8, pw0_); \
        PA1 = __builtin_bit_cast(bf16x8, pw1_); \
    }

// ------------- fused flash-style cross attention (proven r14, 47.7 us) -------------
__global__ __launch_bounds__(256) void attn_k(const u16* __restrict__ Qb,   // [B*T1, F] (pre-scaled)
                                              const u16* __restrict__ Kb,   // [B*T2, F]
                                              const u16* __restrict__ Vt,   // [B*H*DK, T2] (col-permuted)
                                              const int* __restrict__ mask, // [B, T2]
                                              u16* __restrict__ attO) {     // [B*T1, F]
    __shared__ u16 ldsK[2][64 * 64];      // 2 x 8 KB
    __shared__ u16 ldsV[2][64 * 64];      // 2 x 8 KB
    __shared__ float smaskf[T2];          // 8 KB: -16 or -1e30

    const int h = blockIdx.x, q0 = blockIdx.y * 128, b = blockIdx.z;
    const int w = threadIdx.x >> 6, lane = threadIdx.x & 63;
    const int lr = lane & 15, lg = lane >> 4;

    for (int i = threadIdx.x; i < T2; i += 256)
        smaskf[i] = mask[b * T2 + i] ? -16.f : -1e30f;

    // Q fragments (B-operand: lane holds q-row base+lr, d = 8*lg+j)
    const u16* qptrA = Qb + (size_t)(b * T1 + q0 + w * 32 + lr) * F + h * DK + lg * 8;
    const bf16x8 qA0 = *(const bf16x8*)(qptrA);
    const bf16x8 qA1 = *(const bf16x8*)(qptrA + 32);
    const bf16x8 qB0 = *(const bf16x8*)(qptrA + 16 * F);
    const bf16x8 qB1 = *(const bf16x8*)(qptrA + 16 * F + 32);

    // all-ones bf16 A-fragment for the lsum MFMA
    u32x4 ow; ow[0] = ow[1] = ow[2] = ow[3] = 0x3F803F80u;
    const bf16x8 onesf = __builtin_bit_cast(bf16x8, ow);

    // staging: waves 0,1 stage K; waves 2,3 stage V. 4 instrs each.
    const u16* Kg = Kb + (size_t)b * T2 * F + h * DK;
    const u16* Vg = Vt + (size_t)(b * H + h) * DK * T2;
    const int sr = (lane >> 3);          // row-in-instr
    const int scd = lane & 7;            // dest chunk

#define STAGE(BUF, KT) \
    { \
        if (w < 2) { \
            _Pragma("unroll") \
            for (int i_ = 0; i_ < 4; ++i_) { \
                int ii_ = (w & 1) * 4 + i_; \
                int r0_ = ii_ * 8 + sr; \
                int cl_ = scd ^ (r0_ & 7); \
                __builtin_amdgcn_global_load_lds( \
                    (gmem_u32*)(Kg + (size_t)((KT) * 64 + r0_) * F + cl_ * 8), \
                    (lds_u32*)((char*)&ldsK[BUF][0] + ii_ * 1024), 16, 0, 0); \
            } \
        } else { \
            _Pragma("unroll") \
            for (int i_ = 0; i_ < 4; ++i_) { \
                int ii_ = (w & 1) * 4 + i_; \
                int r0_ = ii_ * 8 + sr; \
                int cl_ = scd ^ (r0_ & 7); \
                __builtin_amdgcn_global_load_lds( \
                    (gmem_u32*)(Vg + (size_t)r0_ * T2 + (KT) * 64 + cl_ * 8), \
                    (lds_u32*)((char*)&ldsV[BUF][0] + ii_ * 1024), 16, 0, 0); \
            } \
        } \
    }

    f32x4 oA[4] = {}, oB[4] = {};
    f32x4 lsA4 = {}, lsB4 = {};

    STAGE(0, 0);
    __syncthreads();

    int buf = 0;
    for (int kt = 0; kt < T2 / 64; ++kt) {
        if (kt < T2 / 64 - 1) STAGE(buf ^ 1, kt + 1);

        // ---- fragment reads from LDS (swizzled) ----
        bf16x8 kf[4][2], vf[2][4];
#pragma unroll
        for (int ss = 0; ss < 4; ++ss) {
            int row = ss * 16 + lr;
            kf[ss][0] = *(const bf16x8*)&ldsK[buf][row * 64 + ((lg ^ (row & 7)) * 8)];
            kf[ss][1] = *(const bf16x8*)&ldsK[buf][row * 64 + (((4 + lg) ^ (row & 7)) * 8)];
        }
#pragma unroll
        for (int m = 0; m < 2; ++m)
#pragma unroll
            for (int d = 0; d < 4; ++d) {
                int row = d * 16 + lr;
                vf[m][d] = *(const bf16x8*)&ldsV[buf][row * 64 + (((lg * 2 + m) ^ (row & 7)) * 8)];
            }

        // ---- S^T = K Q^T + C(mask - 16), both q-fragments ----
        f32x4 sA[4], sB[4];
#pragma unroll
        for (int ss = 0; ss < 4; ++ss) {
            f32x4 c = *(const f32x4*)&smaskf[kt * 64 + ss * 16 + lg * 4];
            sA[ss] = c; sB[ss] = c;
        }
        __builtin_amdgcn_s_setprio(1);
#pragma unroll
        for (int ss = 0; ss < 4; ++ss) {
            sA[ss] = __builtin_amdgcn_mfma_f32_16x16x32_bf16(kf[ss][0], qA0, sA[ss], 0, 0, 0);
            sB[ss] = __builtin_amdgcn_mfma_f32_16x16x32_bf16(kf[ss][0], qB0, sB[ss], 0, 0, 0);
            sA[ss] = __builtin_amdgcn_mfma_f32_16x16x32_bf16(kf[ss][1], qA1, sA[ss], 0, 0, 0);
            sB[ss] = __builtin_amdgcn_mfma_f32_16x16x32_bf16(kf[ss][1], qB1, sB[ss], 0, 0, 0);
        }
        __builtin_amdgcn_s_setprio(0);

        // ---- P = 2^S, pack (raw v_exp_f32 + cvt_pk) ----
        bf16x8 paA0, paA1, paB0, paB1;
        SOFTMAX_PACK(sA, paA0, paA1);
        SOFTMAX_PACK(sB, paB0, paB1);

        // ---- O^T += V^T P^T ; lsum += 1^T P^T (ones-MFMA) ----
        __builtin_amdgcn_s_setprio(1);
#pragma unroll
        for (int d = 0; d < 4; ++d) {
            oA[d] = __builtin_amdgcn_mfma_f32_16x16x32_bf16(vf[0][d], paA0, oA[d], 0, 0, 0);
            oB[d] = __builtin_amdgcn_mfma_f32_16x16x32_bf16(vf[0][d], paB0, oB[d], 0, 0, 0);
        }
        lsA4 = __builtin_amdgcn_mfma_f32_16x16x32_bf16(onesf, paA0, lsA4, 0, 0, 0);
        lsB4 = __builtin_amdgcn_mfma_f32_16x16x32_bf16(onesf, paB0, lsB4, 0, 0, 0);
#pragma unroll
        for (int d = 0; d < 4; ++d) {
            oA[d] = __builtin_amdgcn_mfma_f32_16x16x32_bf16(vf[1][d], paA1, oA[d], 0, 0, 0);
            oB[d] = __builtin_amdgcn_mfma_f32_16x16x32_bf16(vf[1][d], paB1, oB[d], 0, 0, 0);
        }
        lsA4 = __builtin_amdgcn_mfma_f32_16x16x32_bf16(onesf, paA1, lsA4, 0, 0, 0);
        lsB4 = __builtin_amdgcn_mfma_f32_16x16x32_bf16(onesf, paB1, lsB4, 0, 0, 0);
        __builtin_amdgcn_s_setprio(0);

        __syncthreads();   // all waves done with buf; next buf staged (vmcnt drain)
        buf ^= 1;
    }

    // ---- epilogue: lsum complete per lane (ones-MFMA); 8B stores ----
    float invA = lsA4[0] > 0.f ? 1.f / lsA4[0] : 1.f;
    float invB = lsB4[0] > 0.f ? 1.f / lsB4[0] : 1.f;
    const size_t obase = (size_t)(b * T1 + q0 + w * 32 + lr) * F + h * DK;
#pragma unroll
    for (int d = 0; d < 4; ++d) {
        ushort4 oa, ob;
        oa.x = f2bf(oA[d][0] * invA); oa.y = f2bf(oA[d][1] * invA);
        oa.z = f2bf(oA[d][2] * invA); oa.w = f2bf(oA[d][3] * invA);
        ob.x = f2bf(oB[d][0] * invB); ob.y = f2bf(oB[d][1] * invB);
        ob.z = f2bf(oB[d][2] * invB); ob.w = f2bf(oB[d][3] * invB);
        *(ushort4*)&attO[obase + d * 16 + lg * 4] = oa;
        *(ushort4*)&attO[obase + 16 * F + d * 16 + lg * 4] = ob;
    }
}

extern "C" void kernel_launch(void* const* d_in, const int* in_sizes, int n_in,
                              void* d_out, int out_size, void* d_ws, size_t ws_size,
                              hipStream_t stream) {
    const float* x      = (const float*)d_in[0];
    const float* memory = (const float*)d_in[1];
    const int*   mmask  = (const int*)d_in[2];
    const float* Wq     = (const float*)d_in[3];
    const float* bq     = (const float*)d_in[4];
    const float* Wkv    = (const float*)d_in[5];
    const float* bkv    = (const float*)d_in[6];
    const float* Wo     = (const float*)d_in[7];
    const float* bo     = (const float*)d_in[8];
    float* out = (float*)d_out;
    char* ws = (char*)d_ws;

    // workspace layout (72 MB total)
    u16* xb   = (u16*)(ws);                  // [4096,1024]  8 MB   (reused as attO)
    u16* mb   = (u16*)(ws + (8u  << 20));    // [8192,1024] 16 MB
    u16* Wqt  = (u16*)(ws + (24u << 20));    // [1024,1024]  2 MB
    u16* Wkvt = (u16*)(ws + (26u << 20));    // [2048,1024]  4 MB
    u16* Wot  = (u16*)(ws + (30u << 20));    // [1024,1024]  2 MB
    u16* Qb   = (u16*)(ws + (32u << 20));    // [4096,1024]  8 MB
    u16* Kb   = (u16*)(ws + (40u << 20));    // [8192,1024] 16 MB
    u16* Vt   = (u16*)(ws + (56u << 20));    // [1024,2048] 16 MB
    u16* attO = xb;

    // 1. casts (x + memory, one launch)
    cast2_bf16_k<<<(B_ * T1 * F + B_ * T2 * F) / 1024, 256, 0, stream>>>(
        x, xb, B_ * T1 * F, memory, mb, B_ * T1 * F + B_ * T2 * F);

    // 2. all weight transposes, one launch
    transpose_cast4_k<<<dim3(F / 64, F / 64, 4), 256, 0, stream>>>(Wq, Wqt, Wo, Wot, Wkv, Wkvt);

    // 3. fused KV + Q projections (Q pre-scaled by 1/sqrt(dk)*log2e)
    gemm_kvq_k<<<dim3(B_ * T2 / 128, 20), 256, 0, stream>>>(
        mb, Wkvt, bkv, Kb, Vt, xb, Wqt, bq, Qb, 0.125f * 1.44269504f);

    // 4. attention (r14 structure: 128-row q-tile, 256 threads)
    attn_k<<<dim3(H, T1 / 128, B_), 256, 0, stream>>>(Qb, Kb, Vt, mmask, attO);

    // 5. output projection (f32 out)
    gemm_k<false, 32, 64><<<dim3(B_ * T1 / 64, F / 128), 256, 0, stream>>>(attO, Wot, bo, 1.f, out, B_ * T1, F, F);
}